// Round 2
// baseline (125.161 us; speedup 1.0000x reference)
//
#include <hip/hip_runtime.h>

// Problem constants (from reference)
constexpr int   NB         = 128;          // bins per axis
constexpr int   NCELL      = NB * NB;      // 16384 cells
constexpr int   NFL        = 2 * NCELL;    // [Dx | Dy] floats = 32768 (de-interleaved)
constexpr float S          = 7.8125f;      // 1000/128, exact in fp32
constexpr int   NUM_NETS   = 100000;
constexpr int   NUM_NODES  = 200000;
constexpr int   NUM_MOVABLE= 180000;
constexpr int   NUM_PINS   = 400000;
constexpr float UNIT_H_CAP = 1.5f;
constexpr float UNIT_V_CAP = 1.4f;

#define TPB    512   // net_diff block size
#define NDB    256   // net_diff blocks: 1/CU (128 KB LDS each)

__device__ __forceinline__ float edgef(int t) { return (float)t * S; }

__device__ __forceinline__ int bin_of(float v) {
    int t = (int)floorf(v / S);
    while (edgef(t + 1) <= v) ++t;
    while (edgef(t)     >  v) --t;
    return t;
}

__device__ __forceinline__ float phi(int t, float lo, float hi) {
    return fminf(fmaxf(edgef(t), lo), hi);
}

// second difference of the clamp-ramp: <=4 nonzeros (indices >=128 dropped by
// caller; they never influence bins 0..127).
__device__ __forceinline__ int second_diff(float lo, float hi,
                                           int* idx, float* val) {
    int a = bin_of(lo);
    int b = bin_of(hi);
    int n = 0;
    idx[n] = a;
    val[n] = phi(a + 1, lo, hi) - 2.f * phi(a, lo, hi) + phi(a - 1, lo, hi);
    ++n;
    idx[n] = a + 1;
    val[n] = phi(a + 2, lo, hi) - 2.f * phi(a + 1, lo, hi) + phi(a, lo, hi);
    ++n;
    if (b > a + 1) {
        idx[n] = b;
        val[n] = phi(b + 1, lo, hi) - 2.f * phi(b, lo, hi) + phi(b - 1, lo, hi);
        ++n;
    }
    if (b > a) {
        idx[n] = b + 1;
        val[n] = phi(b + 2, lo, hi) - 2.f * phi(b + 1, lo, hi) + phi(b, lo, hi);
        ++n;
    }
    return n;
}

// K0: zero the global accumulator (graph-capture-safe replacement for
// hipMemsetAsync). 32 blocks x 256 threads x float4 = 32768 floats.
__global__ __launch_bounds__(256) void zero_kernel(float4* __restrict__ Acc4) {
    Acc4[blockIdx.x * 256 + threadIdx.x] = make_float4(0.f, 0.f, 0.f, 0.f);
}

// K1: fused bbox gather + single-pass LDS-private scatter into DE-INTERLEAVED
// Dx/Dy halves (128 KB dynamic LDS), then SPARSE global atomic flush into the
// single accumulator Acc[2][NCELL] (128 KB, L2-resident).
//
// Net assignment is CONTIGUOUS per block (not round-robin): adjacent lanes
// handle adjacent nets, so nps/net_weights reads coalesce and — since every
// net has exactly 4 pins (s == 4n) — the fnp int4 loads are perfectly
// contiguous 16 B/lane. pin_pos gathers stay random (3.2 MB, L2-resident).
//
// Flush: a large fraction of each block's LDS map is exactly 0 (391 nets x
// <=16 cells), so only nonzero cells are atomically added. Per-block rotation
// decorrelates the address bursts across blocks.
__global__ __launch_bounds__(TPB) void net_diff_kernel(
    const float* __restrict__ pin_pos,
    const float* __restrict__ net_weights,
    const int*   __restrict__ nps,
    const int*   __restrict__ fnp,
    float* __restrict__ Acc) {          // [2][NCELL], pre-zeroed
    extern __shared__ float Dl[];       // [Dx NCELL | Dy NCELL]
    const int tid = threadIdx.x;

    float4* D4 = (float4*)Dl;
    for (int i = tid; i < NFL / 4; i += TPB) D4[i] = make_float4(0, 0, 0, 0);
    __syncthreads();

    const int per = (NUM_NETS + gridDim.x - 1) / gridDim.x;
    const int n0  = blockIdx.x * per;
    const int n1  = min(n0 + per, NUM_NETS);

    for (int n = n0 + tid; n < n1; n += TPB) {
        int s = nps[n], e = nps[n + 1];
        if (e <= s) continue;
        float xmin, xmax, ymin, ymax;
        if (e - s == 4 && (s & 3) == 0) {
            int4 p4 = *(const int4*)(fnp + s);
            float x0 = pin_pos[p4.x], y0 = pin_pos[p4.x + NUM_PINS];
            float x1 = pin_pos[p4.y], y1 = pin_pos[p4.y + NUM_PINS];
            float x2 = pin_pos[p4.z], y2 = pin_pos[p4.z + NUM_PINS];
            float x3 = pin_pos[p4.w], y3 = pin_pos[p4.w + NUM_PINS];
            xmin = fminf(fminf(x0, x1), fminf(x2, x3));
            xmax = fmaxf(fmaxf(x0, x1), fmaxf(x2, x3));
            ymin = fminf(fminf(y0, y1), fminf(y2, y3));
            ymax = fmaxf(fmaxf(y0, y1), fmaxf(y2, y3));
        } else {
            xmin = 1e30f; xmax = -1e30f; ymin = 1e30f; ymax = -1e30f;
            for (int p = s; p < e; ++p) {
                int pin = fnp[p];
                float px = pin_pos[pin];
                float py = pin_pos[pin + NUM_PINS];
                xmin = fminf(xmin, px); xmax = fmaxf(xmax, px);
                ymin = fminf(ymin, py); ymax = fmaxf(ymax, py);
            }
        }
        float w  = net_weights[n];
        float dx = xmax - xmin, dy = ymax - ymin;
        float cx = (dy > 0.f) ? w / dy : 0.f;   // map_x coeff
        float cy = (dx > 0.f) ? w / dx : 0.f;   // map_y coeff
        if (cx == 0.f && cy == 0.f) continue;

        int ixs[4], iys[4];
        float vxs[4], vys[4];
        int nx = second_diff(xmin, xmax, ixs, vxs);
        int ny = second_diff(ymin, ymax, iys, vys);

        for (int i = 0; i < nx; ++i) {
            int row = ixs[i];
            float fi = vxs[i];
            if (fi == 0.f || row >= NB) continue;
            for (int j = 0; j < ny; ++j) {
                int col = iys[j];
                float t = fi * vys[j];
                if (t == 0.f || col >= NB) continue;
                int cell = row * NB + col;
                if (cx != 0.f) atomicAdd(&Dl[cell],         cx * t);
                if (cy != 0.f) atomicAdd(&Dl[NCELL + cell], cy * t);
            }
        }
    }
    __syncthreads();

    // Sparse atomic flush: skip zeros, rotate start per block so the 256
    // blocks don't hammer the same cells at the same instant. Lanes hit
    // consecutive cells -> distinct L2 channels, no intra-wave conflicts.
    const int rot = (blockIdx.x << 6) & (NCELL - 1);   // 256 blocks x 64 = NCELL
    for (int i0 = tid; i0 < NCELL; i0 += TPB) {
        int i = (i0 + rot) & (NCELL - 1);
        float vx = Dl[i];
        float vy = Dl[NCELL + i];
        if (vx != 0.f) atomicAdd(&Acc[i],         vx);
        if (vy != 0.f) atomicAdd(&Acc[NCELL + i], vy);
    }
}

// K3: x-prefix. One block per y-column; thread t = x-row. Reads the single
// accumulator directly (reduce stage eliminated), LDS Hillis-Steele scan
// over 128 rows for both de-interleaved halves.
__global__ __launch_bounds__(NB) void scan_x_kernel(
    const float* __restrict__ Acc,   // [2][NCELL]
    float2* __restrict__ Xp) {       // [NCELL] float2, x-prefixed
    __shared__ float2 sm[NB];
    int col = blockIdx.x;
    int t = threadIdx.x;
    int idx = t * NB + col;
    float2 v = make_float2(Acc[idx], Acc[NCELL + idx]);
    sm[t] = v;
    __syncthreads();
    #pragma unroll
    for (int off = 1; off < NB; off <<= 1) {
        float2 cur = sm[t];
        float2 add = (t >= off) ? sm[t - off] : make_float2(0.f, 0.f);
        __syncthreads();
        cur.x += add.x; cur.y += add.y;
        sm[t] = cur;
        __syncthreads();
    }
    Xp[idx] = sm[t];
}

// K4: y-prefix + clip -> util. One block per x-row; coalesced float2 loads.
__global__ __launch_bounds__(NB) void scan_y_kernel(
    const float2* __restrict__ Xp,   // [NCELL] float2
    float* __restrict__ util) {
    __shared__ float2 sm[NB];
    int row = blockIdx.x;
    int t = threadIdx.x;
    sm[t] = Xp[row * NB + t];
    __syncthreads();
    #pragma unroll
    for (int off = 1; off < NB; off <<= 1) {
        float2 cur = sm[t];
        float2 add = (t >= off) ? sm[t - off] : make_float2(0.f, 0.f);
        __syncthreads();
        cur.x += add.x; cur.y += add.y;
        sm[t] = cur;
        __syncthreads();
    }
    constexpr float invx = 1.f / (S * S * UNIT_H_CAP);
    constexpr float invy = 1.f / (S * S * UNIT_V_CAP);
    float2 r = sm[t];
    float u = fmaxf(r.x * invx, r.y * invy);
    util[row * NB + t] = fminf(fmaxf(u, 0.5f), 2.0f);
}

// K5: per-movable-node area = sum over <=3x3 bins of ox*util*oy
__global__ __launch_bounds__(256) void node_kernel(
    const float* __restrict__ pos,
    const float* __restrict__ nsx,
    const float* __restrict__ nsy,
    const float* __restrict__ util,
    float* __restrict__ out) {
    int m = blockIdx.x * blockDim.x + threadIdx.x;
    if (m >= NUM_MOVABLE) return;
    float x  = pos[m];
    float y  = pos[NUM_NODES + m];
    float xh = x + nsx[m];
    float yh = y + nsy[m];
    int ax = max(0,      (int)floorf(x  / S) - 1);
    int bx = min(NB - 1, (int)floorf(xh / S) + 1);
    int ay = max(0,      (int)floorf(y  / S) - 1);
    int by = min(NB - 1, (int)floorf(yh / S) + 1);
    float acc = 0.f;
    for (int i = ax; i <= bx; ++i) {
        float ov = fminf(edgef(i + 1), xh) - fmaxf(edgef(i), x);
        if (ov <= 0.f) continue;
        float inner = 0.f;
        for (int j = ay; j <= by; ++j) {
            float ovy = fminf(edgef(j + 1), yh) - fmaxf(edgef(j), y);
            if (ovy > 0.f) inner += ovy * util[i * NB + j];
        }
        acc += ov * inner;
    }
    out[m] = acc;
}

extern "C" void kernel_launch(void* const* d_in, const int* in_sizes, int n_in,
                              void* d_out, int out_size, void* d_ws, size_t ws_size,
                              hipStream_t stream) {
    const float* pos      = (const float*)d_in[0];
    const float* pin_pos  = (const float*)d_in[1];
    const float* nsx      = (const float*)d_in[2];
    const float* nsy      = (const float*)d_in[3];
    const float* nw       = (const float*)d_in[4];
    const int*   npstart  = (const int*)d_in[5];
    const int*   fnp      = (const int*)d_in[6];
    float*       out      = (float*)d_out;

    // ws layout (floats): Acc[NFL] | Xp[NFL (float2 per cell)] | util[NCELL]
    float* w    = (float*)d_ws;
    float* Acc  = w;                           w += NFL;
    float* Xp   = w;                           w += NFL;
    float* util = w;                           w += NCELL;
    (void)ws_size;

    (void)hipFuncSetAttribute((const void*)net_diff_kernel,
                              hipFuncAttributeMaxDynamicSharedMemorySize,
                              NFL * (int)sizeof(float));

    // Acc must start at 0 (workspace may be poisoned between runs).
    // Kernel-based zeroing: graph-capture-safe (no hipMemsetAsync).
    zero_kernel<<<NFL / 4 / 256, 256, 0, stream>>>((float4*)Acc);

    net_diff_kernel<<<NDB, TPB, NFL * sizeof(float), stream>>>(
        pin_pos, nw, npstart, fnp, Acc);
    scan_x_kernel<<<NB, NB, 0, stream>>>(Acc, (float2*)Xp);
    scan_y_kernel<<<NB, NB, 0, stream>>>((const float2*)Xp, util);
    node_kernel<<<(NUM_MOVABLE + 255) / 256, 256, 0, stream>>>(
        pos, nsx, nsy, util, out);
}